// Round 1
// baseline (193.831 us; speedup 1.0000x reference)
//
#include <hip/hip_runtime.h>

#define F 128
#define TA 16
#define NSEG 64
#define CAP 512
#define KE 14.3996f

__device__ __forceinline__ float silu_f(float x) {
    return x / (1.0f + expf(-x));
}
__device__ __forceinline__ float softplus_f(float x) {
    return fmaxf(x, 0.0f) + log1pf(expf(-fabsf(x)));
}

// ---------------- Kernel 1: per-atom MLPs (q, c6, rv) + mu projection ----------------
__global__ __launch_bounds__(128) void mlp_kernel(
    const float* __restrict__ h0, const float* __restrict__ h1,
    const int* __restrict__ batch,
    const float* __restrict__ q_w1, const float* __restrict__ q_b1, const float* __restrict__ q_w2,
    const float* __restrict__ vdw_w1, const float* __restrict__ vdw_b1,
    const float* __restrict__ vdw_w2, const float* __restrict__ vdw_b2,
    const float* __restrict__ mu_w,
    float* __restrict__ q_raw, float* __restrict__ c6o, float* __restrict__ rvo,
    float* __restrict__ muo, float* __restrict__ qsum, float* __restrict__ cntf,
    int N)
{
    __shared__ float h0s[TA][F];
    __shared__ float pq[TA][F + 1];   // +1 pad: break 16-way bank conflict in reduce
    __shared__ float pc[TA][F + 1];
    __shared__ float pr[TA][F + 1];
    const int t = threadIdx.x;        // hidden-unit index
    const int base = blockIdx.x * TA;

    #pragma unroll
    for (int a = 0; a < TA; ++a) {
        int n = base + a;
        h0s[a][t] = (n < N) ? h0[(size_t)n * F + t] : 0.0f;
    }
    __syncthreads();

    float accq[TA], accv[TA];
    #pragma unroll
    for (int a = 0; a < TA; ++a) { accq[a] = 0.0f; accv[a] = 0.0f; }

    #pragma unroll 4
    for (int f = 0; f < F; ++f) {
        float wq = q_w1[f * F + t];
        float wv = vdw_w1[f * F + t];
        #pragma unroll
        for (int a = 0; a < TA; ++a) {
            float h = h0s[a][f];      // LDS broadcast
            accq[a] = fmaf(h, wq, accq[a]);
            accv[a] = fmaf(h, wv, accv[a]);
        }
    }

    float bq = q_b1[t], bv = vdw_b1[t];
    float wq2  = q_w2[t];
    float wv2a = vdw_w2[t * 2 + 0], wv2b = vdw_w2[t * 2 + 1];
    #pragma unroll
    for (int a = 0; a < TA; ++a) {
        float sq = silu_f(accq[a] + bq);
        float sv = silu_f(accv[a] + bv);
        pq[a][t] = sq * wq2;
        pc[a][t] = sv * wv2a;
        pr[a][t] = sv * wv2b;
    }
    __syncthreads();

    // reduce 128 partials per atom: 8 threads per atom, 16 serial + 3-step shuffle
    {
        int a = t >> 3, g = t & 7;
        float sumq = 0.f, sumc = 0.f, sumr = 0.f;
        #pragma unroll
        for (int k = 0; k < 16; ++k) {
            int idx = g * 16 + k;
            sumq += pq[a][idx];
            sumc += pc[a][idx];
            sumr += pr[a][idx];
        }
        #pragma unroll
        for (int off = 1; off < 8; off <<= 1) {
            sumq += __shfl_xor(sumq, off, 64);
            sumc += __shfl_xor(sumc, off, 64);
            sumr += __shfl_xor(sumr, off, 64);
        }
        int n = base + a;
        if (g == 0 && n < N) {
            q_raw[n] = sumq;
            c6o[n]   = softplus_f(sumc + vdw_b2[0]);
            rvo[n]   = softplus_f(sumr + vdw_b2[1]);
            int s = batch[n];
            atomicAdd(&qsum[s], sumq);
            atomicAdd(&cntf[s], 1.0f);
        }
    }

    // mu[n][c] = h1[n][c][:] . mu_w   — one wave per 8 atoms
    {
        int lane = t & 63, wave = t >> 6;
        float wm0 = mu_w[lane];
        float wm1 = mu_w[lane + 64];
        for (int a8 = 0; a8 < 8; ++a8) {
            int n = base + wave * 8 + a8;
            if (n >= N) break;
            #pragma unroll
            for (int c = 0; c < 3; ++c) {
                const float* row = h1 + ((size_t)n * 3 + c) * F;
                float p = row[lane] * wm0 + row[lane + 64] * wm1;
                #pragma unroll
                for (int off = 1; off < 64; off <<= 1)
                    p += __shfl_xor(p, off, 64);
                if (lane == 0) muo[n * 3 + c] = p;
            }
        }
    }
}

// ---------------- Kernel 2: segment means + starts (batch is sorted) ----------------
__global__ __launch_bounds__(64) void seg_kernel(
    const float* __restrict__ qsum, const float* __restrict__ cntf,
    float* __restrict__ mean, int* __restrict__ seg_start, int* __restrict__ seg_cnt)
{
    int l = threadIdx.x;              // one lane per segment, NSEG==64
    float c = cntf[l];
    mean[l] = qsum[l] / fmaxf(c, 1.0f);
    int ci = (int)(c + 0.5f);
    int x = ci;
    #pragma unroll
    for (int off = 1; off < 64; off <<= 1) {
        int v = __shfl_up(x, off, 64);
        if (l >= off) x += v;
    }
    seg_start[l] = x - ci;            // exclusive prefix sum
    seg_cnt[l]   = ci;
}

// ---------------- Kernel 3: per-segment pairwise energy ----------------
template <bool USE_LDS>
__device__ float seg_energy_loop(int start, unsigned ns, float mn,
    float inv_s2s, float inv_sig,
    const float* __restrict__ pos, const float* __restrict__ qr,
    const float* __restrict__ c6a, const float* __restrict__ rva,
    const float* __restrict__ mua,
    const float* sx, const float* sy, const float* sz,
    const float* sqv, const float* scv, const float* srw,
    const float* smx, const float* smy, const float* smz)
{
    float e = 0.0f;
    unsigned p = threadIdx.x;
    unsigned i = p / ns;
    unsigned j = p - i * ns;
    while (i < ns) {
        if (i != j) {
            float xi, yi, zi, qi, ci, ri, mxi, myi, mzi;
            float xj, yj, zj, qj, cj, rj, mxj, myj, mzj;
            if constexpr (USE_LDS) {
                xi = sx[i]; yi = sy[i]; zi = sz[i];
                qi = sqv[i]; ci = scv[i]; ri = srw[i];
                mxi = smx[i]; myi = smy[i]; mzi = smz[i];
                xj = sx[j]; yj = sy[j]; zj = sz[j];
                qj = sqv[j]; cj = scv[j]; rj = srw[j];
                mxj = smx[j]; myj = smy[j]; mzj = smz[j];
            } else {
                int gi = start + (int)i, gj = start + (int)j;
                xi = pos[gi * 3]; yi = pos[gi * 3 + 1]; zi = pos[gi * 3 + 2];
                qi = qr[gi] - mn; ci = c6a[gi]; ri = rva[gi];
                mxi = mua[gi * 3]; myi = mua[gi * 3 + 1]; mzi = mua[gi * 3 + 2];
                xj = pos[gj * 3]; yj = pos[gj * 3 + 1]; zj = pos[gj * 3 + 2];
                qj = qr[gj] - mn; cj = c6a[gj]; rj = rva[gj];
                mxj = mua[gj * 3]; myj = mua[gj * 3 + 1]; mzj = mua[gj * 3 + 2];
            }
            float dx = xi - xj, dy = yi - yj, dz = zi - zj;
            float d2 = dx * dx + dy * dy + dz * dz;
            float dist = sqrtf(d2 + 1e-8f);
            float inv = 1.0f / dist;
            // shielded Coulomb
            e += 0.5f * KE * qi * qj * inv * erff(dist * inv_s2s);
            // damped London dispersion: rv_ij^6 == (rv_i*rv_j)^3
            float c6ij = sqrtf(ci * cj);
            float rr = ri * rj;
            float damp = d2 * d2 * d2 + rr * rr * rr;
            e -= 0.5f * c6ij / damp;
            // dipole-dipole
            float nx = dx * inv, ny = dy * inv, nz = dz * inv;
            float mdm = mxi * mxj + myi * myj + mzi * mzj;
            float a1 = mxi * nx + myi * ny + mzi * nz;
            float a2 = mxj * nx + myj * ny + mzj * nz;
            float er = erff(dist * inv_sig);
            float rad = inv * inv * inv * er * er * er;
            e += 0.5f * KE * (mdm - 3.0f * a1 * a2) * rad;
        }
        j += 256;
        while (j >= ns) { j -= ns; ++i; }
    }
    return e;
}

__global__ __launch_bounds__(256) void pair_kernel(
    const float* __restrict__ pos, const float* __restrict__ qr,
    const float* __restrict__ c6a, const float* __restrict__ rva,
    const float* __restrict__ mua, const float* __restrict__ mean,
    const int* __restrict__ seg_start, const int* __restrict__ seg_cnt,
    const float* __restrict__ sigma_p, float* __restrict__ out)
{
    __shared__ float sx[CAP], sy[CAP], sz[CAP], sqv[CAP], scv[CAP], srw[CAP];
    __shared__ float smx[CAP], smy[CAP], smz[CAP];
    int s = blockIdx.x;
    int start = seg_start[s];
    int ns = seg_cnt[s];
    float e = 0.0f;
    if (ns >= 2) {
        float mn = mean[s];
        float sig = sigma_p[0];
        float inv_s2s = 1.0f / (1.41421356237f * sig);
        float inv_sig = 1.0f / sig;
        bool use_lds = (ns <= CAP);
        if (use_lds) {
            for (int jj = threadIdx.x; jj < ns; jj += 256) {
                int n = start + jj;
                sx[jj] = pos[n * 3]; sy[jj] = pos[n * 3 + 1]; sz[jj] = pos[n * 3 + 2];
                sqv[jj] = qr[n] - mn; scv[jj] = c6a[n]; srw[jj] = rva[n];
                smx[jj] = mua[n * 3]; smy[jj] = mua[n * 3 + 1]; smz[jj] = mua[n * 3 + 2];
            }
        }
        __syncthreads();
        if (use_lds)
            e = seg_energy_loop<true >(start, (unsigned)ns, mn, inv_s2s, inv_sig,
                                       pos, qr, c6a, rva, mua,
                                       sx, sy, sz, sqv, scv, srw, smx, smy, smz);
        else
            e = seg_energy_loop<false>(start, (unsigned)ns, mn, inv_s2s, inv_sig,
                                       pos, qr, c6a, rva, mua,
                                       sx, sy, sz, sqv, scv, srw, smx, smy, smz);
    }
    // block reduction -> single atomic per block
    #pragma unroll
    for (int off = 32; off > 0; off >>= 1) e += __shfl_xor(e, off, 64);
    __shared__ float wsum[4];
    if ((threadIdx.x & 63) == 0) wsum[threadIdx.x >> 6] = e;
    __syncthreads();
    if (threadIdx.x == 0) atomicAdd(out, wsum[0] + wsum[1] + wsum[2] + wsum[3]);
}

extern "C" void kernel_launch(void* const* d_in, const int* in_sizes, int n_in,
                              void* d_out, int out_size, void* d_ws, size_t ws_size,
                              hipStream_t stream) {
    const float* h0     = (const float*)d_in[0];
    const float* h1     = (const float*)d_in[1];
    const float* pos    = (const float*)d_in[2];
    const int*   batch  = (const int*)d_in[3];
    const float* q_w1   = (const float*)d_in[4];
    const float* q_b1   = (const float*)d_in[5];
    const float* q_w2   = (const float*)d_in[6];
    const float* sigma  = (const float*)d_in[7];
    const float* vdw_w1 = (const float*)d_in[8];
    const float* vdw_b1 = (const float*)d_in[9];
    const float* vdw_w2 = (const float*)d_in[10];
    const float* vdw_b2 = (const float*)d_in[11];
    const float* mu_w   = (const float*)d_in[12];

    int N = in_sizes[0] / F;

    float* ws     = (float*)d_ws;
    float* q_raw  = ws;
    float* c6     = ws + (size_t)N;
    float* rv     = ws + (size_t)2 * N;
    float* mu     = ws + (size_t)3 * N;       // 3N floats
    float* qsum   = ws + (size_t)6 * N;       // 64
    float* cntf   = qsum + NSEG;              // 64
    float* mean   = qsum + 2 * NSEG;          // 64
    int*   sstart = (int*)(qsum + 3 * NSEG);  // 64
    int*   scnt   = sstart + NSEG;            // 64

    // zero the accumulators (ws and d_out are poisoned 0xAA before every launch)
    hipMemsetAsync(qsum, 0, 2 * NSEG * sizeof(float), stream);
    hipMemsetAsync(d_out, 0, sizeof(float), stream);

    int blocksA = (N + TA - 1) / TA;
    mlp_kernel<<<blocksA, 128, 0, stream>>>(h0, h1, batch,
        q_w1, q_b1, q_w2, vdw_w1, vdw_b1, vdw_w2, vdw_b2, mu_w,
        q_raw, c6, rv, mu, qsum, cntf, N);

    seg_kernel<<<1, 64, 0, stream>>>(qsum, cntf, mean, sstart, scnt);

    pair_kernel<<<NSEG, 256, 0, stream>>>(pos, q_raw, c6, rv, mu, mean,
        sstart, scnt, sigma, (float*)d_out);
}

// Round 2
// 156.975 us; speedup vs baseline: 1.2348x; 1.2348x over previous
//
#include <hip/hip_runtime.h>

#define F 128
#define TA 8          // atoms per mlp block
#define NSEG 64
#define CAP 512       // max atoms per segment staged in LDS
#define SPLIT 8       // blocks per segment in pair kernel
#define KE 14.3996f

__device__ __forceinline__ float silu_f(float x) {
    return x / (1.0f + expf(-x));
}
__device__ __forceinline__ float softplus_f(float x) {
    return fmaxf(x, 0.0f) + log1pf(expf(-fabsf(x)));
}

// ---------------- Kernel 1: per-atom MLPs (q, c6, rv) + mu projection ----------------
// 256 threads: t=tid&127 is the hidden unit, m=tid>>7 selects q-MLP (0) / vdw-MLP (1).
__global__ __launch_bounds__(256) void mlp_kernel(
    const float* __restrict__ h0, const float* __restrict__ h1,
    const int* __restrict__ batch,
    const float* __restrict__ q_w1, const float* __restrict__ q_b1, const float* __restrict__ q_w2,
    const float* __restrict__ vdw_w1, const float* __restrict__ vdw_b1,
    const float* __restrict__ vdw_w2, const float* __restrict__ vdw_b2,
    const float* __restrict__ mu_w,
    float* __restrict__ q_raw, float* __restrict__ c6o, float* __restrict__ rvo,
    float* __restrict__ muo, float* __restrict__ qsum,
    int N)
{
    __shared__ float h0s[TA][F];          // 4 KB
    __shared__ float pp[3][TA][F + 4];    // partials: 0=q, 1=c6, 2=rv (pad 4 vs bank conflicts)
    const int tid = threadIdx.x;
    const int t = tid & 127;
    const int m = tid >> 7;
    const int base = blockIdx.x * TA;

    // ---- stage h0 tile: 8 atoms x 128 floats = 256 float4, one per thread ----
    {
        int a = tid >> 5;                 // tid/(F/4)
        if (base + a < N) {
            const float4* src = (const float4*)(h0 + (size_t)base * F);
            ((float4*)&h0s[0][0])[tid] = src[tid];
        } else {
            ((float4*)&h0s[0][0])[tid] = make_float4(0.f, 0.f, 0.f, 0.f);
        }
    }
    __syncthreads();

    // ---- hidden layer: acc[a] = sum_f h0s[a][f] * W1[f][t] ----
    const float* __restrict__ W1 = m ? vdw_w1 : q_w1;
    float acc[TA];
    #pragma unroll
    for (int a = 0; a < TA; ++a) acc[a] = 0.0f;

    #pragma unroll 8
    for (int f = 0; f < F; ++f) {
        float w = W1[f * F + t];
        #pragma unroll
        for (int a = 0; a < TA; ++a)
            acc[a] = fmaf(h0s[a][f], w, acc[a]);
    }

    // ---- activation + layer-2 partials into LDS ----
    if (m == 0) {
        float b = q_b1[t], w2 = q_w2[t];
        #pragma unroll
        for (int a = 0; a < TA; ++a)
            pp[0][a][t] = silu_f(acc[a] + b) * w2;
    } else {
        float b = vdw_b1[t];
        float w2a = vdw_w2[2 * t], w2b = vdw_w2[2 * t + 1];
        #pragma unroll
        for (int a = 0; a < TA; ++a) {
            float s = silu_f(acc[a] + b);
            pp[1][a][t] = s * w2a;
            pp[2][a][t] = s * w2b;
        }
    }
    __syncthreads();

    // ---- reduce 24 scalars (8 atoms x {q,c6,rv}), 8 threads each ----
    {
        int sid = tid >> 3;               // 0..31, need 0..23
        int g = tid & 7;
        if (sid < 24) {
            int o = sid >> 3;             // 0..2
            int a = sid & 7;
            const float* row = &pp[o][a][0];
            float sum = 0.0f;
            #pragma unroll
            for (int k = 0; k < 16; ++k)
                sum += row[g + 8 * k];
            #pragma unroll
            for (int off = 1; off < 8; off <<= 1)
                sum += __shfl_xor(sum, off, 64);
            int n = base + a;
            if (g == 0 && n < N) {
                if (o == 0) {
                    q_raw[n] = sum;
                    atomicAdd(&qsum[batch[n]], sum);
                } else if (o == 1) {
                    c6o[n] = softplus_f(sum + vdw_b2[0]);
                } else {
                    rvo[n] = softplus_f(sum + vdw_b2[1]);
                }
            }
        }
    }

    // ---- mu: each wave handles 2 atoms x 3 components (interleaved for ILP) ----
    {
        int lane = tid & 63, wid = tid >> 6;
        float wm0 = mu_w[lane];
        float wm1 = mu_w[lane + 64];
        #pragma unroll
        for (int r = 0; r < 2; ++r) {
            int n = base + wid * 2 + r;
            if (n < N) {
                const float* row = h1 + (size_t)n * 3 * F;
                float p0 = row[lane]         * wm0 + row[lane + 64]         * wm1;
                float p1 = row[F + lane]     * wm0 + row[F + lane + 64]     * wm1;
                float p2 = row[2 * F + lane] * wm0 + row[2 * F + lane + 64] * wm1;
                #pragma unroll
                for (int off = 1; off < 64; off <<= 1) {
                    p0 += __shfl_xor(p0, off, 64);
                    p1 += __shfl_xor(p1, off, 64);
                    p2 += __shfl_xor(p2, off, 64);
                }
                if (lane == 0) {
                    muo[n * 3 + 0] = p0;
                    muo[n * 3 + 1] = p1;
                    muo[n * 3 + 2] = p2;
                }
            }
        }
    }
}

// ---------------- Kernel 2: segment starts/counts via binary search + means ----------------
__global__ __launch_bounds__(64) void seg_kernel(
    const int* __restrict__ batch, const float* __restrict__ qsum,
    float* __restrict__ mean, int* __restrict__ seg_start, int* __restrict__ seg_cnt, int N)
{
    int s = threadIdx.x;                  // one lane per segment (NSEG==64)
    // lower_bound(batch, s)
    int lo = 0, hi = N;
    while (lo < hi) { int mid = (lo + hi) >> 1; if (batch[mid] < s) lo = mid + 1; else hi = mid; }
    int lo2 = lo, hi2 = N;
    while (lo2 < hi2) { int mid = (lo2 + hi2) >> 1; if (batch[mid] < s + 1) lo2 = mid + 1; else hi2 = mid; }
    seg_start[s] = lo;
    int c = lo2 - lo;
    seg_cnt[s] = c;
    mean[s] = qsum[s] / fmaxf((float)c, 1.0f);
}

// ---------------- Kernel 3: per-segment pairwise energy ----------------
template <bool USE_LDS>
__device__ float seg_energy_loop(int start, unsigned ns, unsigned chunk, float mn,
    float inv_s2s, float inv_sig,
    const float* __restrict__ pos, const float* __restrict__ qr,
    const float* __restrict__ c6a, const float* __restrict__ rva,
    const float* __restrict__ mua,
    const float* sx, const float* sy, const float* sz,
    const float* sqv, const float* scv, const float* srw,
    const float* smx, const float* smy, const float* smz)
{
    float e = 0.0f;
    unsigned total = ns * ns;
    unsigned stride = SPLIT * 256u;
    unsigned p = chunk * 256u + threadIdx.x;
    if (p >= total) return 0.0f;
    unsigned i = p / ns;                  // one div, then incremental stepping
    unsigned j = p - i * ns;
    unsigned di = stride / ns;
    unsigned dj = stride - di * ns;       // stride % ns
    while (i < ns) {
        if (i != j) {
            float xi, yi, zi, qi, ci, ri, mxi, myi, mzi;
            float xj, yj, zj, qj, cj, rj, mxj, myj, mzj;
            if constexpr (USE_LDS) {
                xi = sx[i]; yi = sy[i]; zi = sz[i];
                qi = sqv[i]; ci = scv[i]; ri = srw[i];
                mxi = smx[i]; myi = smy[i]; mzi = smz[i];
                xj = sx[j]; yj = sy[j]; zj = sz[j];
                qj = sqv[j]; cj = scv[j]; rj = srw[j];
                mxj = smx[j]; myj = smy[j]; mzj = smz[j];
            } else {
                int gi = start + (int)i, gj = start + (int)j;
                xi = pos[gi * 3]; yi = pos[gi * 3 + 1]; zi = pos[gi * 3 + 2];
                qi = qr[gi] - mn; ci = c6a[gi]; ri = rva[gi];
                mxi = mua[gi * 3]; myi = mua[gi * 3 + 1]; mzi = mua[gi * 3 + 2];
                xj = pos[gj * 3]; yj = pos[gj * 3 + 1]; zj = pos[gj * 3 + 2];
                qj = qr[gj] - mn; cj = c6a[gj]; rj = rva[gj];
                mxj = mua[gj * 3]; myj = mua[gj * 3 + 1]; mzj = mua[gj * 3 + 2];
            }
            float dx = xi - xj, dy = yi - yj, dz = zi - zj;
            float d2 = dx * dx + dy * dy + dz * dz;
            float dist = sqrtf(d2 + 1e-8f);
            float inv = 1.0f / dist;
            // shielded Coulomb
            e += 0.5f * KE * qi * qj * inv * erff(dist * inv_s2s);
            // damped London dispersion: rv_ij^6 == (rv_i*rv_j)^3
            float c6ij = sqrtf(ci * cj);
            float rr = ri * rj;
            float damp = d2 * d2 * d2 + rr * rr * rr;
            e -= 0.5f * c6ij / damp;
            // dipole-dipole
            float nx = dx * inv, ny = dy * inv, nz = dz * inv;
            float mdm = mxi * mxj + myi * myj + mzi * mzj;
            float a1 = mxi * nx + myi * ny + mzi * nz;
            float a2 = mxj * nx + myj * ny + mzj * nz;
            float er = erff(dist * inv_sig);
            float rad = inv * inv * inv * er * er * er;
            e += 0.5f * KE * (mdm - 3.0f * a1 * a2) * rad;
        }
        i += di; j += dj;
        if (j >= ns) { j -= ns; ++i; }
    }
    return e;
}

__global__ __launch_bounds__(256) void pair_kernel(
    const float* __restrict__ pos, const float* __restrict__ qr,
    const float* __restrict__ c6a, const float* __restrict__ rva,
    const float* __restrict__ mua, const float* __restrict__ mean,
    const int* __restrict__ seg_start, const int* __restrict__ seg_cnt,
    const float* __restrict__ sigma_p, float* __restrict__ out)
{
    __shared__ float sx[CAP], sy[CAP], sz[CAP], sqv[CAP], scv[CAP], srw[CAP];
    __shared__ float smx[CAP], smy[CAP], smz[CAP];
    int s = blockIdx.x & (NSEG - 1);      // consecutive blocks -> different segments (XCD spread)
    unsigned chunk = blockIdx.x >> 6;
    int start = seg_start[s];
    int ns = seg_cnt[s];
    float e = 0.0f;
    if (ns >= 2) {
        float mn = mean[s];
        float sig = sigma_p[0];
        float inv_s2s = 1.0f / (1.41421356237f * sig);
        float inv_sig = 1.0f / sig;
        bool use_lds = (ns <= CAP);
        if (use_lds) {
            for (int jj = threadIdx.x; jj < ns; jj += 256) {
                int n = start + jj;
                sx[jj] = pos[n * 3]; sy[jj] = pos[n * 3 + 1]; sz[jj] = pos[n * 3 + 2];
                sqv[jj] = qr[n] - mn; scv[jj] = c6a[n]; srw[jj] = rva[n];
                smx[jj] = mua[n * 3]; smy[jj] = mua[n * 3 + 1]; smz[jj] = mua[n * 3 + 2];
            }
        }
        __syncthreads();
        if (use_lds)
            e = seg_energy_loop<true >(start, (unsigned)ns, chunk, mn, inv_s2s, inv_sig,
                                       pos, qr, c6a, rva, mua,
                                       sx, sy, sz, sqv, scv, srw, smx, smy, smz);
        else
            e = seg_energy_loop<false>(start, (unsigned)ns, chunk, mn, inv_s2s, inv_sig,
                                       pos, qr, c6a, rva, mua,
                                       sx, sy, sz, sqv, scv, srw, smx, smy, smz);
    }
    // block reduction -> single atomic per block
    #pragma unroll
    for (int off = 32; off > 0; off >>= 1) e += __shfl_xor(e, off, 64);
    __shared__ float wsum[4];
    if ((threadIdx.x & 63) == 0) wsum[threadIdx.x >> 6] = e;
    __syncthreads();
    if (threadIdx.x == 0) atomicAdd(out, wsum[0] + wsum[1] + wsum[2] + wsum[3]);
}

extern "C" void kernel_launch(void* const* d_in, const int* in_sizes, int n_in,
                              void* d_out, int out_size, void* d_ws, size_t ws_size,
                              hipStream_t stream) {
    const float* h0     = (const float*)d_in[0];
    const float* h1     = (const float*)d_in[1];
    const float* pos    = (const float*)d_in[2];
    const int*   batch  = (const int*)d_in[3];
    const float* q_w1   = (const float*)d_in[4];
    const float* q_b1   = (const float*)d_in[5];
    const float* q_w2   = (const float*)d_in[6];
    const float* sigma  = (const float*)d_in[7];
    const float* vdw_w1 = (const float*)d_in[8];
    const float* vdw_b1 = (const float*)d_in[9];
    const float* vdw_w2 = (const float*)d_in[10];
    const float* vdw_b2 = (const float*)d_in[11];
    const float* mu_w   = (const float*)d_in[12];

    int N = in_sizes[0] / F;

    float* ws     = (float*)d_ws;
    float* q_raw  = ws;
    float* c6     = ws + (size_t)N;
    float* rv     = ws + (size_t)2 * N;
    float* mu     = ws + (size_t)3 * N;       // 3N floats
    float* qsum   = ws + (size_t)6 * N;       // 64
    float* mean   = qsum + NSEG;              // 64
    int*   sstart = (int*)(qsum + 2 * NSEG);  // 64
    int*   scnt   = sstart + NSEG;            // 64

    // zero the accumulators (ws and d_out are poisoned 0xAA before every launch)
    hipMemsetAsync(qsum, 0, NSEG * sizeof(float), stream);
    hipMemsetAsync(d_out, 0, sizeof(float), stream);

    int blocksA = (N + TA - 1) / TA;
    mlp_kernel<<<blocksA, 256, 0, stream>>>(h0, h1, batch,
        q_w1, q_b1, q_w2, vdw_w1, vdw_b1, vdw_w2, vdw_b2, mu_w,
        q_raw, c6, rv, mu, qsum, N);

    seg_kernel<<<1, 64, 0, stream>>>(batch, qsum, mean, sstart, scnt, N);

    pair_kernel<<<NSEG * SPLIT, 256, 0, stream>>>(pos, q_raw, c6, rv, mu, mean,
        sstart, scnt, sigma, (float*)d_out);
}

// Round 3
// 120.574 us; speedup vs baseline: 1.6076x; 1.3019x over previous
//
#include <hip/hip_runtime.h>

#define F 128
#define TA 16         // atoms per mlp block
#define NSEG 64
#define CAP 512       // max atoms per segment staged in LDS
#define SPLIT 8       // blocks per segment in pair kernel
#define NPAIRBLK (NSEG * SPLIT)
#define KE 14.3996f

__device__ __forceinline__ float silu_f(float x) {
    return x / (1.0f + expf(-x));
}
__device__ __forceinline__ float softplus_f(float x) {
    return fmaxf(x, 0.0f) + log1pf(expf(-fabsf(x)));
}

// ---------------- Kernel 1: per-atom MLPs (q, c6, rv) + mu projection ----------------
// 256 threads. m=tid>>7 picks MLP (0=q, 1=vdw). hq=tid&31 owns hidden units 4hq..4hq+3
// (float4 weight loads). as=(tid>>5)&3 owns atoms {as, as+4, as+8, as+12}.
// Layer-1 sums complete in-registers; layer-2 reduces across the 32 hq lanes only.
__global__ __launch_bounds__(256) void mlp_kernel(
    const float* __restrict__ h0, const float* __restrict__ h1,
    const int* __restrict__ batch,
    const float* __restrict__ q_w1, const float* __restrict__ q_b1, const float* __restrict__ q_w2,
    const float* __restrict__ vdw_w1, const float* __restrict__ vdw_b1,
    const float* __restrict__ vdw_w2, const float* __restrict__ vdw_b2,
    const float* __restrict__ mu_w,
    float* __restrict__ q_raw, float* __restrict__ c6o, float* __restrict__ rvo,
    float* __restrict__ muo, float* __restrict__ qsum,
    int N)
{
    __shared__ float h0s[TA][F];          // 8 KB
    __shared__ float qa[TA];              // per-atom q for block-level segment aggregation
    const int tid = threadIdx.x;
    const int m  = tid >> 7;              // wave-uniform (waves 0,1 -> q; 2,3 -> vdw)
    const int hq = tid & 31;
    const int as = (tid >> 5) & 3;
    const int base = blockIdx.x * TA;

    // ---- stage h0 tile: 16 atoms x 128 floats = 512 float4, 2 per thread ----
    {
        const float4* src = (const float4*)(h0 + (size_t)base * F);
        float4* dst = (float4*)&h0s[0][0];
        #pragma unroll
        for (int r = 0; r < 2; ++r) {
            int idx = tid + r * 256;
            int a = idx >> 5;
            dst[idx] = (base + a < N) ? src[idx] : make_float4(0.f, 0.f, 0.f, 0.f);
        }
    }
    __syncthreads();

    // ---- layer 1: acc[k][j] = sum_f h0[atom_k][f] * W1[f][4hq+j] ----
    const float4* __restrict__ W1v = (const float4*)(m ? vdw_w1 : q_w1);
    float acc[4][4];
    #pragma unroll
    for (int k = 0; k < 4; ++k)
        #pragma unroll
        for (int j = 0; j < 4; ++j) acc[k][j] = 0.0f;

    #pragma unroll 4
    for (int f = 0; f < F; ++f) {
        float4 w = W1v[f * 32 + hq];
        float hv[4];
        #pragma unroll
        for (int k = 0; k < 4; ++k) hv[k] = h0s[as + 4 * k][f];
        #pragma unroll
        for (int k = 0; k < 4; ++k) {
            acc[k][0] = fmaf(hv[k], w.x, acc[k][0]);
            acc[k][1] = fmaf(hv[k], w.y, acc[k][1]);
            acc[k][2] = fmaf(hv[k], w.z, acc[k][2]);
            acc[k][3] = fmaf(hv[k], w.w, acc[k][3]);
        }
    }

    // ---- activation + layer 2 + 32-lane reduction ----
    if (m == 0) {
        float4 b  = ((const float4*)q_b1)[hq];
        float4 w2 = ((const float4*)q_w2)[hq];
        float part[4];
        #pragma unroll
        for (int k = 0; k < 4; ++k) {
            part[k] = silu_f(acc[k][0] + b.x) * w2.x
                    + silu_f(acc[k][1] + b.y) * w2.y
                    + silu_f(acc[k][2] + b.z) * w2.z
                    + silu_f(acc[k][3] + b.w) * w2.w;
        }
        #pragma unroll
        for (int off = 16; off > 0; off >>= 1)
            #pragma unroll
            for (int k = 0; k < 4; ++k)
                part[k] += __shfl_xor(part[k], off, 64);
        if (hq == 0) {
            #pragma unroll
            for (int k = 0; k < 4; ++k) {
                int a = as + 4 * k, n = base + a;
                float v = (n < N) ? part[k] : 0.0f;
                qa[a] = v;
                if (n < N) q_raw[n] = v;
            }
        }
    } else {
        float4 b  = ((const float4*)vdw_b1)[hq];
        float4 wA = ((const float4*)vdw_w2)[2 * hq];      // (c6w,rvw) for units 4hq,4hq+1
        float4 wB = ((const float4*)vdw_w2)[2 * hq + 1];  // units 4hq+2,4hq+3
        float pc[4], pr[4];
        #pragma unroll
        for (int k = 0; k < 4; ++k) {
            float s0 = silu_f(acc[k][0] + b.x);
            float s1 = silu_f(acc[k][1] + b.y);
            float s2 = silu_f(acc[k][2] + b.z);
            float s3 = silu_f(acc[k][3] + b.w);
            pc[k] = s0 * wA.x + s1 * wA.z + s2 * wB.x + s3 * wB.z;
            pr[k] = s0 * wA.y + s1 * wA.w + s2 * wB.y + s3 * wB.w;
        }
        #pragma unroll
        for (int off = 16; off > 0; off >>= 1)
            #pragma unroll
            for (int k = 0; k < 4; ++k) {
                pc[k] += __shfl_xor(pc[k], off, 64);
                pr[k] += __shfl_xor(pr[k], off, 64);
            }
        if (hq == 0) {
            float b2c = vdw_b2[0], b2r = vdw_b2[1];
            #pragma unroll
            for (int k = 0; k < 4; ++k) {
                int n = base + as + 4 * k;
                if (n < N) {
                    c6o[n] = softplus_f(pc[k] + b2c);
                    rvo[n] = softplus_f(pr[k] + b2r);
                }
            }
        }
    }

    // ---- mu: wave w handles atoms base+4w..base+4w+3, float2 loads + 6-step shuffle ----
    {
        int lane = tid & 63, wid = tid >> 6;
        float2 wm = ((const float2*)mu_w)[lane];
        #pragma unroll
        for (int r = 0; r < 4; ++r) {
            int n = base + wid * 4 + r;
            if (n < N) {                                  // wave-uniform
                const float2* row = (const float2*)(h1 + (size_t)n * 3 * F);
                float2 v0 = row[lane], v1 = row[64 + lane], v2 = row[128 + lane];
                float p0 = v0.x * wm.x + v0.y * wm.y;
                float p1 = v1.x * wm.x + v1.y * wm.y;
                float p2 = v2.x * wm.x + v2.y * wm.y;
                #pragma unroll
                for (int off = 1; off < 64; off <<= 1) {
                    p0 += __shfl_xor(p0, off, 64);
                    p1 += __shfl_xor(p1, off, 64);
                    p2 += __shfl_xor(p2, off, 64);
                }
                if (lane == 0) {
                    muo[n * 3 + 0] = p0;
                    muo[n * 3 + 1] = p1;
                    muo[n * 3 + 2] = p2;
                }
            }
        }
    }

    // ---- block-level segment aggregation of q: ~1-2 atomics per block ----
    __syncthreads();
    if (tid == 0) {
        int i = 0;
        while (i < TA && base + i < N) {
            int s = batch[base + i];
            float sum = 0.0f;
            while (i < TA && base + i < N && batch[base + i] == s) { sum += qa[i]; ++i; }
            atomicAdd(&qsum[s], sum);
        }
    }
}

// ---------------- Kernel 2: segment starts/counts via binary search + means ----------------
__global__ __launch_bounds__(64) void seg_kernel(
    const int* __restrict__ batch, const float* __restrict__ qsum,
    float* __restrict__ mean, int* __restrict__ seg_start, int* __restrict__ seg_cnt, int N)
{
    int s = threadIdx.x;                  // one lane per segment (NSEG==64)
    int lo = 0, hi = N;
    while (lo < hi) { int mid = (lo + hi) >> 1; if (batch[mid] < s) lo = mid + 1; else hi = mid; }
    int lo2 = lo, hi2 = N;
    while (lo2 < hi2) { int mid = (lo2 + hi2) >> 1; if (batch[mid] < s + 1) lo2 = mid + 1; else hi2 = mid; }
    seg_start[s] = lo;
    int c = lo2 - lo;
    seg_cnt[s] = c;
    mean[s] = qsum[s] / fmaxf((float)c, 1.0f);
}

// ---------------- Kernel 3: per-segment pairwise energy (partials, no atomics) ----------------
template <bool USE_LDS>
__device__ float seg_energy_loop(int start, unsigned ns, unsigned chunk, float mn,
    float inv_s2s, float inv_sig,
    const float* __restrict__ pos, const float* __restrict__ qr,
    const float* __restrict__ c6a, const float* __restrict__ rva,
    const float* __restrict__ mua,
    const float* sx, const float* sy, const float* sz,
    const float* sqv, const float* scv, const float* srw,
    const float* smx, const float* smy, const float* smz)
{
    float e = 0.0f;
    unsigned total = ns * ns;
    unsigned stride = SPLIT * 256u;
    unsigned p = chunk * 256u + threadIdx.x;
    if (p >= total) return 0.0f;
    unsigned i = p / ns;
    unsigned j = p - i * ns;
    unsigned di = stride / ns;
    unsigned dj = stride - di * ns;
    while (i < ns) {
        if (i != j) {
            float xi, yi, zi, qi, ci, ri, mxi, myi, mzi;
            float xj, yj, zj, qj, cj, rj, mxj, myj, mzj;
            if constexpr (USE_LDS) {
                xi = sx[i]; yi = sy[i]; zi = sz[i];
                qi = sqv[i]; ci = scv[i]; ri = srw[i];
                mxi = smx[i]; myi = smy[i]; mzi = smz[i];
                xj = sx[j]; yj = sy[j]; zj = sz[j];
                qj = sqv[j]; cj = scv[j]; rj = srw[j];
                mxj = smx[j]; myj = smy[j]; mzj = smz[j];
            } else {
                int gi = start + (int)i, gj = start + (int)j;
                xi = pos[gi * 3]; yi = pos[gi * 3 + 1]; zi = pos[gi * 3 + 2];
                qi = qr[gi] - mn; ci = c6a[gi]; ri = rva[gi];
                mxi = mua[gi * 3]; myi = mua[gi * 3 + 1]; mzi = mua[gi * 3 + 2];
                xj = pos[gj * 3]; yj = pos[gj * 3 + 1]; zj = pos[gj * 3 + 2];
                qj = qr[gj] - mn; cj = c6a[gj]; rj = rva[gj];
                mxj = mua[gj * 3]; myj = mua[gj * 3 + 1]; mzj = mua[gj * 3 + 2];
            }
            float dx = xi - xj, dy = yi - yj, dz = zi - zj;
            float d2 = dx * dx + dy * dy + dz * dz;
            float dist = sqrtf(d2 + 1e-8f);
            float inv = 1.0f / dist;
            // shielded Coulomb
            e += 0.5f * KE * qi * qj * inv * erff(dist * inv_s2s);
            // damped London dispersion: rv_ij^6 == (rv_i*rv_j)^3
            float c6ij = sqrtf(ci * cj);
            float rr = ri * rj;
            float damp = d2 * d2 * d2 + rr * rr * rr;
            e -= 0.5f * c6ij / damp;
            // dipole-dipole
            float nx = dx * inv, ny = dy * inv, nz = dz * inv;
            float mdm = mxi * mxj + myi * myj + mzi * mzj;
            float a1 = mxi * nx + myi * ny + mzi * nz;
            float a2 = mxj * nx + myj * ny + mzj * nz;
            float er = erff(dist * inv_sig);
            float rad = inv * inv * inv * er * er * er;
            e += 0.5f * KE * (mdm - 3.0f * a1 * a2) * rad;
        }
        i += di; j += dj;
        if (j >= ns) { j -= ns; ++i; }
    }
    return e;
}

__global__ __launch_bounds__(256) void pair_kernel(
    const float* __restrict__ pos, const float* __restrict__ qr,
    const float* __restrict__ c6a, const float* __restrict__ rva,
    const float* __restrict__ mua, const float* __restrict__ mean,
    const int* __restrict__ seg_start, const int* __restrict__ seg_cnt,
    const float* __restrict__ sigma_p, float* __restrict__ pairpart)
{
    __shared__ float sx[CAP], sy[CAP], sz[CAP], sqv[CAP], scv[CAP], srw[CAP];
    __shared__ float smx[CAP], smy[CAP], smz[CAP];
    int s = blockIdx.x & (NSEG - 1);
    unsigned chunk = blockIdx.x >> 6;
    int start = seg_start[s];
    int ns = seg_cnt[s];
    float e = 0.0f;
    if (ns >= 2) {
        float mn = mean[s];
        float sig = sigma_p[0];
        float inv_s2s = 1.0f / (1.41421356237f * sig);
        float inv_sig = 1.0f / sig;
        bool use_lds = (ns <= CAP);
        if (use_lds) {
            for (int jj = threadIdx.x; jj < ns; jj += 256) {
                int n = start + jj;
                sx[jj] = pos[n * 3]; sy[jj] = pos[n * 3 + 1]; sz[jj] = pos[n * 3 + 2];
                sqv[jj] = qr[n] - mn; scv[jj] = c6a[n]; srw[jj] = rva[n];
                smx[jj] = mua[n * 3]; smy[jj] = mua[n * 3 + 1]; smz[jj] = mua[n * 3 + 2];
            }
        }
        __syncthreads();
        if (use_lds)
            e = seg_energy_loop<true >(start, (unsigned)ns, chunk, mn, inv_s2s, inv_sig,
                                       pos, qr, c6a, rva, mua,
                                       sx, sy, sz, sqv, scv, srw, smx, smy, smz);
        else
            e = seg_energy_loop<false>(start, (unsigned)ns, chunk, mn, inv_s2s, inv_sig,
                                       pos, qr, c6a, rva, mua,
                                       sx, sy, sz, sqv, scv, srw, smx, smy, smz);
    }
    // block reduction -> one partial per block (no global atomics)
    #pragma unroll
    for (int off = 32; off > 0; off >>= 1) e += __shfl_xor(e, off, 64);
    __shared__ float wsum[4];
    if ((threadIdx.x & 63) == 0) wsum[threadIdx.x >> 6] = e;
    __syncthreads();
    if (threadIdx.x == 0) pairpart[blockIdx.x] = wsum[0] + wsum[1] + wsum[2] + wsum[3];
}

// ---------------- Kernel 4: final reduction of block partials ----------------
__global__ __launch_bounds__(256) void final_kernel(
    const float* __restrict__ pairpart, float* __restrict__ out, int n)
{
    float e = 0.0f;
    for (int i = threadIdx.x; i < n; i += 256) e += pairpart[i];
    #pragma unroll
    for (int off = 32; off > 0; off >>= 1) e += __shfl_xor(e, off, 64);
    __shared__ float wsum[4];
    if ((threadIdx.x & 63) == 0) wsum[threadIdx.x >> 6] = e;
    __syncthreads();
    if (threadIdx.x == 0) out[0] = wsum[0] + wsum[1] + wsum[2] + wsum[3];
}

extern "C" void kernel_launch(void* const* d_in, const int* in_sizes, int n_in,
                              void* d_out, int out_size, void* d_ws, size_t ws_size,
                              hipStream_t stream) {
    const float* h0     = (const float*)d_in[0];
    const float* h1     = (const float*)d_in[1];
    const float* pos    = (const float*)d_in[2];
    const int*   batch  = (const int*)d_in[3];
    const float* q_w1   = (const float*)d_in[4];
    const float* q_b1   = (const float*)d_in[5];
    const float* q_w2   = (const float*)d_in[6];
    const float* sigma  = (const float*)d_in[7];
    const float* vdw_w1 = (const float*)d_in[8];
    const float* vdw_b1 = (const float*)d_in[9];
    const float* vdw_w2 = (const float*)d_in[10];
    const float* vdw_b2 = (const float*)d_in[11];
    const float* mu_w   = (const float*)d_in[12];

    int N = in_sizes[0] / F;

    float* ws     = (float*)d_ws;
    float* q_raw  = ws;
    float* c6     = ws + (size_t)N;
    float* rv     = ws + (size_t)2 * N;
    float* mu     = ws + (size_t)3 * N;       // 3N floats
    float* qsum   = ws + (size_t)6 * N;       // 64
    float* mean   = qsum + NSEG;              // 64
    int*   sstart = (int*)(qsum + 2 * NSEG);  // 64
    int*   scnt   = sstart + NSEG;            // 64
    float* ppart  = (float*)(scnt + NSEG);    // NPAIRBLK

    hipMemsetAsync(qsum, 0, NSEG * sizeof(float), stream);

    int blocksA = (N + TA - 1) / TA;
    mlp_kernel<<<blocksA, 256, 0, stream>>>(h0, h1, batch,
        q_w1, q_b1, q_w2, vdw_w1, vdw_b1, vdw_w2, vdw_b2, mu_w,
        q_raw, c6, rv, mu, qsum, N);

    seg_kernel<<<1, 64, 0, stream>>>(batch, qsum, mean, sstart, scnt, N);

    pair_kernel<<<NPAIRBLK, 256, 0, stream>>>(pos, q_raw, c6, rv, mu, mean,
        sstart, scnt, sigma, ppart);

    final_kernel<<<1, 256, 0, stream>>>(ppart, (float*)d_out, NPAIRBLK);
}

// Round 4
// 114.325 us; speedup vs baseline: 1.6954x; 1.0547x over previous
//
#include <hip/hip_runtime.h>

#define F 128
#define TA 8          // atoms per mlp block
#define NSEG 64
#define CAP 256       // max atoms per segment staged in LDS (seg avg ~96)
#define SPLIT 8       // blocks per segment in pair kernel
#define NPAIRBLK (NSEG * SPLIT)
#define KE 14.3996f

__device__ __forceinline__ float silu_f(float x) {
    return x / (1.0f + expf(-x));
}
__device__ __forceinline__ float softplus_f(float x) {
    return fmaxf(x, 0.0f) + log1pf(expf(-fabsf(x)));
}

// ---------------- Kernel 1: per-atom MLPs (q, c6, rv) + mu projection + seg scan ----------------
// 256 threads. m=tid>>7 picks MLP (0=q, 1=vdw). hq=tid&31 owns hidden units 4hq..4hq+3.
// as=(tid>>5)&3 owns atoms {as, as+4}. No atomics anywhere.
__global__ __launch_bounds__(256) void mlp_kernel(
    const float* __restrict__ h0, const float* __restrict__ h1,
    const int* __restrict__ batch,
    const float* __restrict__ q_w1, const float* __restrict__ q_b1, const float* __restrict__ q_w2,
    const float* __restrict__ vdw_w1, const float* __restrict__ vdw_b1,
    const float* __restrict__ vdw_w2, const float* __restrict__ vdw_b2,
    const float* __restrict__ mu_w,
    float* __restrict__ q_raw, float* __restrict__ c6o, float* __restrict__ rvo,
    float* __restrict__ muo, int* __restrict__ seg_start, int* __restrict__ seg_cnt,
    int N)
{
    __shared__ float h0s[TA][F];          // 4 KB
    const int tid = threadIdx.x;
    const int m  = tid >> 7;              // wave-uniform (waves 0,1 -> q; 2,3 -> vdw)
    const int hq = tid & 31;
    const int as = (tid >> 5) & 3;
    const int base = blockIdx.x * TA;

    // ---- stage h0 tile: 8 atoms x 128 floats = 256 float4, one per thread ----
    {
        const float4* src = (const float4*)(h0 + (size_t)base * F);
        int a = tid >> 5;
        ((float4*)&h0s[0][0])[tid] =
            (base + a < N) ? src[tid] : make_float4(0.f, 0.f, 0.f, 0.f);
    }
    __syncthreads();

    // ---- layer 1: acc[k][j] = sum_f h0[atom][f] * W1[f][4hq+j], atoms {as, as+4} ----
    const float4* __restrict__ W1v = (const float4*)(m ? vdw_w1 : q_w1);
    float acc[2][4];
    #pragma unroll
    for (int k = 0; k < 2; ++k)
        #pragma unroll
        for (int j = 0; j < 4; ++j) acc[k][j] = 0.0f;

    #pragma unroll 4
    for (int f = 0; f < F; ++f) {
        float4 w = W1v[f * 32 + hq];
        float hv0 = h0s[as][f];
        float hv1 = h0s[as + 4][f];
        acc[0][0] = fmaf(hv0, w.x, acc[0][0]);
        acc[0][1] = fmaf(hv0, w.y, acc[0][1]);
        acc[0][2] = fmaf(hv0, w.z, acc[0][2]);
        acc[0][3] = fmaf(hv0, w.w, acc[0][3]);
        acc[1][0] = fmaf(hv1, w.x, acc[1][0]);
        acc[1][1] = fmaf(hv1, w.y, acc[1][1]);
        acc[1][2] = fmaf(hv1, w.z, acc[1][2]);
        acc[1][3] = fmaf(hv1, w.w, acc[1][3]);
    }

    // ---- activation + layer 2 + 32-lane reduction ----
    if (m == 0) {
        float4 b  = ((const float4*)q_b1)[hq];
        float4 w2 = ((const float4*)q_w2)[hq];
        float part[2];
        #pragma unroll
        for (int k = 0; k < 2; ++k) {
            part[k] = silu_f(acc[k][0] + b.x) * w2.x
                    + silu_f(acc[k][1] + b.y) * w2.y
                    + silu_f(acc[k][2] + b.z) * w2.z
                    + silu_f(acc[k][3] + b.w) * w2.w;
        }
        #pragma unroll
        for (int off = 16; off > 0; off >>= 1)
            #pragma unroll
            for (int k = 0; k < 2; ++k)
                part[k] += __shfl_xor(part[k], off, 64);
        if (hq == 0) {
            #pragma unroll
            for (int k = 0; k < 2; ++k) {
                int n = base + as + 4 * k;
                if (n < N) q_raw[n] = part[k];
            }
        }
    } else {
        float4 b  = ((const float4*)vdw_b1)[hq];
        float4 wA = ((const float4*)vdw_w2)[2 * hq];      // (c6w,rvw) for units 4hq,4hq+1
        float4 wB = ((const float4*)vdw_w2)[2 * hq + 1];  // units 4hq+2,4hq+3
        float pc[2], pr[2];
        #pragma unroll
        for (int k = 0; k < 2; ++k) {
            float s0 = silu_f(acc[k][0] + b.x);
            float s1 = silu_f(acc[k][1] + b.y);
            float s2 = silu_f(acc[k][2] + b.z);
            float s3 = silu_f(acc[k][3] + b.w);
            pc[k] = s0 * wA.x + s1 * wA.z + s2 * wB.x + s3 * wB.z;
            pr[k] = s0 * wA.y + s1 * wA.w + s2 * wB.y + s3 * wB.w;
        }
        #pragma unroll
        for (int off = 16; off > 0; off >>= 1)
            #pragma unroll
            for (int k = 0; k < 2; ++k) {
                pc[k] += __shfl_xor(pc[k], off, 64);
                pr[k] += __shfl_xor(pr[k], off, 64);
            }
        if (hq == 0) {
            float b2c = vdw_b2[0], b2r = vdw_b2[1];
            #pragma unroll
            for (int k = 0; k < 2; ++k) {
                int n = base + as + 4 * k;
                if (n < N) {
                    c6o[n] = softplus_f(pc[k] + b2c);
                    rvo[n] = softplus_f(pr[k] + b2r);
                }
            }
        }
    }

    // ---- mu: wave w handles atoms base+2w, base+2w+1; float2 loads + 6-step shuffle ----
    {
        int lane = tid & 63, wid = tid >> 6;
        float2 wm = ((const float2*)mu_w)[lane];
        #pragma unroll
        for (int r = 0; r < 2; ++r) {
            int n = base + wid * 2 + r;
            if (n < N) {                                  // wave-uniform
                const float2* row = (const float2*)(h1 + (size_t)n * 3 * F);
                float2 v0 = row[lane], v1 = row[64 + lane], v2 = row[128 + lane];
                float p0 = v0.x * wm.x + v0.y * wm.y;
                float p1 = v1.x * wm.x + v1.y * wm.y;
                float p2 = v2.x * wm.x + v2.y * wm.y;
                #pragma unroll
                for (int off = 1; off < 64; off <<= 1) {
                    p0 += __shfl_xor(p0, off, 64);
                    p1 += __shfl_xor(p1, off, 64);
                    p2 += __shfl_xor(p2, off, 64);
                }
                if (lane == 0) {
                    muo[n * 3 + 0] = p0;
                    muo[n * 3 + 1] = p1;
                    muo[n * 3 + 2] = p2;
                }
            }
        }
    }

    // ---- block 0, wave 0: segment starts/counts via binary search (tail work,
    //      overlaps the other 767 blocks; read by pair_kernel after launch boundary) ----
    if (blockIdx.x == 0 && tid < NSEG) {
        int s = tid;
        int lo = 0, hi = N;
        while (lo < hi) { int mid = (lo + hi) >> 1; if (batch[mid] < s) lo = mid + 1; else hi = mid; }
        int lo2 = lo, hi2 = N;
        while (lo2 < hi2) { int mid = (lo2 + hi2) >> 1; if (batch[mid] < s + 1) lo2 = mid + 1; else hi2 = mid; }
        seg_start[s] = lo;
        seg_cnt[s]   = lo2 - lo;
    }
}

// ---------------- Kernel 2: per-segment pairwise energy (self-sufficient, no atomics) ----------------
template <bool USE_LDS>
__device__ float seg_energy_loop(int start, unsigned ns, unsigned chunk, float mn,
    float inv_s2s, float inv_sig,
    const float* __restrict__ pos, const float* __restrict__ qr,
    const float* __restrict__ c6a, const float* __restrict__ rva,
    const float* __restrict__ mua,
    const float* spos, const float* smu,
    const float* sq, const float* sc, const float* sr)
{
    float e = 0.0f;
    unsigned total = ns * ns;
    unsigned stride = SPLIT * 256u;
    unsigned p = chunk * 256u + threadIdx.x;
    if (p >= total) return 0.0f;
    unsigned i = p / ns;
    unsigned j = p - i * ns;
    unsigned di = stride / ns;
    unsigned dj = stride - di * ns;
    while (i < ns) {
        if (i != j) {
            float xi, yi, zi, qi, ci, ri, mxi, myi, mzi;
            float xj, yj, zj, qj, cj, rj, mxj, myj, mzj;
            if constexpr (USE_LDS) {
                xi = spos[3 * i]; yi = spos[3 * i + 1]; zi = spos[3 * i + 2];
                qi = sq[i]; ci = sc[i]; ri = sr[i];
                mxi = smu[3 * i]; myi = smu[3 * i + 1]; mzi = smu[3 * i + 2];
                xj = spos[3 * j]; yj = spos[3 * j + 1]; zj = spos[3 * j + 2];
                qj = sq[j]; cj = sc[j]; rj = sr[j];
                mxj = smu[3 * j]; myj = smu[3 * j + 1]; mzj = smu[3 * j + 2];
            } else {
                int gi = start + (int)i, gj = start + (int)j;
                xi = pos[gi * 3]; yi = pos[gi * 3 + 1]; zi = pos[gi * 3 + 2];
                qi = qr[gi] - mn; ci = c6a[gi]; ri = rva[gi];
                mxi = mua[gi * 3]; myi = mua[gi * 3 + 1]; mzi = mua[gi * 3 + 2];
                xj = pos[gj * 3]; yj = pos[gj * 3 + 1]; zj = pos[gj * 3 + 2];
                qj = qr[gj] - mn; cj = c6a[gj]; rj = rva[gj];
                mxj = mua[gj * 3]; myj = mua[gj * 3 + 1]; mzj = mua[gj * 3 + 2];
            }
            float dx = xi - xj, dy = yi - yj, dz = zi - zj;
            float d2 = dx * dx + dy * dy + dz * dz;
            float dist = sqrtf(d2 + 1e-8f);
            float inv = 1.0f / dist;
            // shielded Coulomb
            e += 0.5f * KE * qi * qj * inv * erff(dist * inv_s2s);
            // damped London dispersion: rv_ij^6 == (rv_i*rv_j)^3
            float c6ij = sqrtf(ci * cj);
            float rr = ri * rj;
            float damp = d2 * d2 * d2 + rr * rr * rr;
            e -= 0.5f * c6ij / damp;
            // dipole-dipole
            float nx = dx * inv, ny = dy * inv, nz = dz * inv;
            float mdm = mxi * mxj + myi * myj + mzi * mzj;
            float a1 = mxi * nx + myi * ny + mzi * nz;
            float a2 = mxj * nx + myj * ny + mzj * nz;
            float er = erff(dist * inv_sig);
            float rad = inv * inv * inv * er * er * er;
            e += 0.5f * KE * (mdm - 3.0f * a1 * a2) * rad;
        }
        i += di; j += dj;
        if (j >= ns) { j -= ns; ++i; }
    }
    return e;
}

__global__ __launch_bounds__(256) void pair_kernel(
    const float* __restrict__ pos, const float* __restrict__ qr,
    const float* __restrict__ c6a, const float* __restrict__ rva,
    const float* __restrict__ mua,
    const int* __restrict__ seg_start, const int* __restrict__ seg_cnt,
    const float* __restrict__ sigma_p, float* __restrict__ pairpart)
{
    __shared__ float spos[3 * CAP], smu[3 * CAP], sq[CAP], sc[CAP], sr[CAP];
    __shared__ float red[4];
    __shared__ float s_mean;
    const int tid = threadIdx.x;
    int s = blockIdx.x & (NSEG - 1);
    unsigned chunk = blockIdx.x >> 6;
    int start = seg_start[s];
    int ns = seg_cnt[s];
    float e = 0.0f;
    if (ns >= 2) {
        float sig = sigma_p[0];
        float inv_s2s = 1.0f / (1.41421356237f * sig);
        float inv_sig = 1.0f / sig;
        bool use_lds = (ns <= CAP);            // block-uniform
        float mn = 0.0f;
        if (use_lds) {
            // coalesced flat staging (pos/mu contiguous per segment)
            for (int jj = tid; jj < 3 * ns; jj += 256) {
                spos[jj] = pos[3 * start + jj];
                smu[jj]  = mua[3 * start + jj];
            }
            for (int jj = tid; jj < ns; jj += 256) {
                sq[jj] = qr[start + jj];
                sc[jj] = c6a[start + jj];
                sr[jj] = rva[start + jj];
            }
            __syncthreads();
            // block-level mean of q
            float ms = 0.0f;
            for (int jj = tid; jj < ns; jj += 256) ms += sq[jj];
            #pragma unroll
            for (int off = 32; off > 0; off >>= 1) ms += __shfl_xor(ms, off, 64);
            if ((tid & 63) == 0) red[tid >> 6] = ms;
            __syncthreads();
            if (tid == 0) s_mean = (red[0] + red[1] + red[2] + red[3]) / (float)ns;
            __syncthreads();
            float m = s_mean;
            for (int jj = tid; jj < ns; jj += 256) sq[jj] -= m;
            __syncthreads();
        } else {
            // global fallback: mean from global reads
            float ms = 0.0f;
            for (int jj = tid; jj < ns; jj += 256) ms += qr[start + jj];
            #pragma unroll
            for (int off = 32; off > 0; off >>= 1) ms += __shfl_xor(ms, off, 64);
            if ((tid & 63) == 0) red[tid >> 6] = ms;
            __syncthreads();
            if (tid == 0) s_mean = (red[0] + red[1] + red[2] + red[3]) / (float)ns;
            __syncthreads();
            mn = s_mean;
        }
        if (use_lds)
            e = seg_energy_loop<true >(start, (unsigned)ns, chunk, mn, inv_s2s, inv_sig,
                                       pos, qr, c6a, rva, mua, spos, smu, sq, sc, sr);
        else
            e = seg_energy_loop<false>(start, (unsigned)ns, chunk, mn, inv_s2s, inv_sig,
                                       pos, qr, c6a, rva, mua, spos, smu, sq, sc, sr);
    }
    // block reduction -> one partial per block (no global atomics)
    #pragma unroll
    for (int off = 32; off > 0; off >>= 1) e += __shfl_xor(e, off, 64);
    __shared__ float wsum[4];
    if ((tid & 63) == 0) wsum[tid >> 6] = e;
    __syncthreads();
    if (tid == 0) pairpart[blockIdx.x] = wsum[0] + wsum[1] + wsum[2] + wsum[3];
}

// ---------------- Kernel 3: final reduction of block partials ----------------
__global__ __launch_bounds__(256) void final_kernel(
    const float* __restrict__ pairpart, float* __restrict__ out, int n)
{
    float e = 0.0f;
    for (int i = threadIdx.x; i < n; i += 256) e += pairpart[i];
    #pragma unroll
    for (int off = 32; off > 0; off >>= 1) e += __shfl_xor(e, off, 64);
    __shared__ float wsum[4];
    if ((threadIdx.x & 63) == 0) wsum[threadIdx.x >> 6] = e;
    __syncthreads();
    if (threadIdx.x == 0) out[0] = wsum[0] + wsum[1] + wsum[2] + wsum[3];
}

extern "C" void kernel_launch(void* const* d_in, const int* in_sizes, int n_in,
                              void* d_out, int out_size, void* d_ws, size_t ws_size,
                              hipStream_t stream) {
    const float* h0     = (const float*)d_in[0];
    const float* h1     = (const float*)d_in[1];
    const float* pos    = (const float*)d_in[2];
    const int*   batch  = (const int*)d_in[3];
    const float* q_w1   = (const float*)d_in[4];
    const float* q_b1   = (const float*)d_in[5];
    const float* q_w2   = (const float*)d_in[6];
    const float* sigma  = (const float*)d_in[7];
    const float* vdw_w1 = (const float*)d_in[8];
    const float* vdw_b1 = (const float*)d_in[9];
    const float* vdw_w2 = (const float*)d_in[10];
    const float* vdw_b2 = (const float*)d_in[11];
    const float* mu_w   = (const float*)d_in[12];

    int N = in_sizes[0] / F;

    float* ws     = (float*)d_ws;
    float* q_raw  = ws;
    float* c6     = ws + (size_t)N;
    float* rv     = ws + (size_t)2 * N;
    float* mu     = ws + (size_t)3 * N;       // 3N floats
    int*   sstart = (int*)(ws + (size_t)6 * N);  // 64
    int*   scnt   = sstart + NSEG;               // 64
    float* ppart  = (float*)(scnt + NSEG);       // NPAIRBLK

    int blocksA = (N + TA - 1) / TA;
    mlp_kernel<<<blocksA, 256, 0, stream>>>(h0, h1, batch,
        q_w1, q_b1, q_w2, vdw_w1, vdw_b1, vdw_w2, vdw_b2, mu_w,
        q_raw, c6, rv, mu, sstart, scnt, N);

    pair_kernel<<<NPAIRBLK, 256, 0, stream>>>(pos, q_raw, c6, rv, mu,
        sstart, scnt, sigma, ppart);

    final_kernel<<<1, 256, 0, stream>>>(ppart, (float*)d_out, NPAIRBLK);
}